// Round 6
// baseline (19309.276 us; speedup 1.0000x reference)
//
#include <hip/hip_runtime.h>
#include <math.h>

// RNN with short-term plasticity: persistent cooperative kernel, 1 grid
// barrier per time step.
//
// Round 6: identical to round 5 EXCEPT __launch_bounds__(512, 1).
// Round 5's launch_bounds(512,2) capped the allocator at 128 VGPRs
// (VGPR_Count=128 in rocprof for BOTH rounds 4+5); the w[8][16] kernel
// needs ~230 -> ~100 spilled regs re-fetched from scratch every step =
// the observed 21.9 GB FETCH_SIZE / 19 ms regression. With the cap at
// 256 (1 WG/CU is forced anyway) the round-5 plan actually runs:
// 128 WGs x 8 owned neurons -> coherent A broadcast 16 MB/step (half of
// round 4), barrier poll traffic 4x lower.
//
#define NH 1024
#define NB 32
#define NI 8
#define NO 8
#define TSTEPS 1000

#define NWG 128
#define BLK 512

// d_out float offsets (z, h, r, u concatenated flat)
#define OFF_Z 0
#define OFF_H (NB * TSTEPS * NO)            // 256000
#define OFF_R (OFF_H + NB * TSTEPS * NH)    // 33024000
#define OFF_U (OFF_R + NB * TSTEPS * NH)    // 65792000

// d_ws float offsets: slots[128] (128B apart), AT[2][NH][NB], HT[2][NB][NH]
#define WS_AT (NWG * 32)                    // 4096 floats
#define WS_HT (WS_AT + 2 * NH * NB)

typedef unsigned long long u64;

// Barrier: WG g stamps its own slot (plain coherent store, no RMW);
// 128 poller threads each watch one slot. Release ordering: the leading
// __syncthreads drains vmcnt (agent stores ack'd at the coherence point)
// in every wave before any wave passes s_barrier; trailing __syncthreads
// keeps post-barrier loads from starting early.
__device__ __forceinline__ void gridbar(unsigned* slot, int g, unsigned stamp) {
    __syncthreads();
    if (threadIdx.x == 0)
        __hip_atomic_store(&slot[g * 32], stamp,
                           __ATOMIC_RELAXED, __HIP_MEMORY_SCOPE_AGENT);
    if (threadIdx.x < NWG) {
        while (__hip_atomic_load(&slot[threadIdx.x * 32],
                                 __ATOMIC_RELAXED, __HIP_MEMORY_SCOPE_AGENT) < stamp)
            __builtin_amdgcn_s_sleep(1);
    }
    __syncthreads();
}

__global__ __launch_bounds__(BLK, 1) void rnn_stp_kernel(
    const float* __restrict__ x,     // [32][1000][8]
    const float* __restrict__ h0,    // [32][1024]
    const float* __restrict__ r0,    // [32][1024]
    const float* __restrict__ u0,    // [32][1024]
    const float* __restrict__ prel,  // [1024]
    const float* __restrict__ scal,  // [1024]
    const float* __restrict__ Wih,   // [1024][8]
    const float* __restrict__ Whh,   // [1024][1024]
    const float* __restrict__ Wmask, // [1024][1024]
    const float* __restrict__ Whz,   // [8][1024]
    float* __restrict__ out,
    float* __restrict__ ws)
{
    const int tid = threadIdx.x;
    const int g   = blockIdx.x;

    unsigned* slot = (unsigned*)ws;
    float* AT = ws + WS_AT;   // [2][NH][NB]
    float* HT = ws + WS_HT;   // [2][NB][NH]

    // XCD swizzle: XCD x (= g&7) owns neurons [128x, 128x+128) so 64B output
    // lines (16 neurons) are fully assembled within one XCD's L2.
    const int chunk = (g & 7) * 16 + (g >> 3);
    const int ib = chunk * 8;                 // first of 8 owned neurons

    __shared__ float4 red4[8 * 72];           // [wid][il*9+bg]
    __shared__ float zred[2][2][4];           // [parity][half][wid&3]

    // ---- GEMM roles: ks = tid>>3 (j in [ks*16,+16)), bg = tid&7 (4 b) ----
    const int ks = tid >> 3;
    const int bg = tid & 7;

    // Weights for 8 owned rows x this thread's 16-j slice (128 VGPRs).
    float w[8][16];
    #pragma unroll
    for (int il = 0; il < 8; ++il) {
        const float* wp = Whh   + (ib + il) * NH + ks * 16;
        const float* mp = Wmask + (ib + il) * NH + ks * 16;
        #pragma unroll
        for (int jj = 0; jj < 16; ++jj) w[il][jj] = wp[jj] * mp[jj];
    }

    // ---- z roles: WG g handles pairs 2g (tid<256) and 2g+1 (tid>=256) ----
    const int half = tid >> 8;       // 0 or 1
    const int zt   = tid & 255;      // thread index within the pair
    const int pair = 2 * g + half;
    const int bz = pair >> 3, oz = pair & 7;
    const float4 wzv = *(const float4*)(Whz + oz * NH + 4 * zt);

    // ---- owner role: tid<256, b = tid>>3, neuron = ib + (tid&7) ----
    const bool own = tid < 256;
    const int ob   = tid >> 3;
    const int il_o = tid & 7;
    const int oi   = ib + il_o;
    float h = 0.f, r = 0.f, u = 0.f, htr = 0.f, p = 0.f, sc = 0.f;
    float wih[8];
    if (own) {
        h  = h0[ob * NH + oi];
        r  = r0[ob * NH + oi];
        u  = u0[ob * NH + oi];
        p  = prel[oi];
        sc = scal[oi];
        #pragma unroll
        for (int k = 0; k < 8; ++k) wih[k] = Wih[oi * NI + k];
        htr = tanhf(h);
        __hip_atomic_store(&AT[oi * NB + ob], r * sc * htr,
                           __ATOMIC_RELAXED, __HIP_MEMORY_SCOPE_AGENT);
    }

    unsigned stamp = 1;
    gridbar(slot, g, stamp); ++stamp;

    const int lane = tid & 63, wid = tid >> 6;

    for (int t = 0; t < TSTEPS; ++t) {
        // ---- x prefetch (cached, read-only; consumed in owner section) ----
        float4 xa = make_float4(0.f, 0.f, 0.f, 0.f), xb = xa;
        if (own) {
            const float4* xp = (const float4*)(x + (ob * TSTEPS + t) * NI);
            xa = xp[0];
            xb = xp[1];
        }

        // ---- coherent A loads + FMAs: unique 16 j x 4 b slice ----
        const float* Ab = AT + (t & 1) * NH * NB + (ks * 16) * NB + bg * 4;
        float acc[8][4];
        #pragma unroll
        for (int il = 0; il < 8; ++il) {
            #pragma unroll
            for (int q = 0; q < 4; ++q) acc[il][q] = 0.f;
        }
        #pragma unroll
        for (int jc = 0; jc < 4; ++jc) {
            float2 a0[4], a1[4];
            #pragma unroll
            for (int j4 = 0; j4 < 4; ++j4) {
                const float* ap = Ab + (jc * 4 + j4) * NB;
                a0[j4] = __builtin_bit_cast(float2,
                    __hip_atomic_load((const u64*)ap,
                                      __ATOMIC_RELAXED, __HIP_MEMORY_SCOPE_AGENT));
                a1[j4] = __builtin_bit_cast(float2,
                    __hip_atomic_load((const u64*)(ap + 2),
                                      __ATOMIC_RELAXED, __HIP_MEMORY_SCOPE_AGENT));
            }
            #pragma unroll
            for (int j4 = 0; j4 < 4; ++j4) {
                const int jj = jc * 4 + j4;
                #pragma unroll
                for (int il = 0; il < 8; ++il) {
                    const float wv = w[il][jj];
                    acc[il][0] = fmaf(a0[j4].x, wv, acc[il][0]);
                    acc[il][1] = fmaf(a0[j4].y, wv, acc[il][1]);
                    acc[il][2] = fmaf(a1[j4].x, wv, acc[il][2]);
                    acc[il][3] = fmaf(a1[j4].y, wv, acc[il][3]);
                }
            }
        }

        // ---- in-wave butterfly over ks low bits (lane bits 3..5) ----
        #pragma unroll
        for (int m = 8; m <= 32; m <<= 1) {
            #pragma unroll
            for (int il = 0; il < 8; ++il) {
                #pragma unroll
                for (int q = 0; q < 4; ++q)
                    acc[il][q] += __shfl_xor(acc[il][q], m, 64);
            }
        }
        if (lane < 8) {   // lane == bg
            #pragma unroll
            for (int il = 0; il < 8; ++il)
                red4[wid * 72 + il * 9 + lane] =
                    make_float4(acc[il][0], acc[il][1], acc[il][2], acc[il][3]);
        }
        __syncthreads();

        // ---- finalize z[t-2] (zred written at step t-1, gridbar-ordered) ----
        if (t >= 2 && zt == 0) {
            const int fpar = t & 1;   // == (t-2)&1
            float z = zred[fpar][half][0] + zred[fpar][half][1]
                    + zred[fpar][half][2] + zred[fpar][half][3];
            out[OFF_Z + (bz * TSTEPS + (t - 2)) * NO + oz] = z;
        }
        // ---- partial z[t-1] from HT[(t-1)&1] ----
        if (t >= 1) {
            const int par = (t - 1) & 1;
            const float* HTp = HT + par * NB * NH + bz * NH + 4 * zt;
            float2 b0 = __builtin_bit_cast(float2,
                __hip_atomic_load((const u64*)HTp,
                                  __ATOMIC_RELAXED, __HIP_MEMORY_SCOPE_AGENT));
            float2 b1 = __builtin_bit_cast(float2,
                __hip_atomic_load((const u64*)(HTp + 2),
                                  __ATOMIC_RELAXED, __HIP_MEMORY_SCOPE_AGENT));
            float zp = fmaf(b0.x, wzv.x, fmaf(b0.y, wzv.y,
                       fmaf(b1.x, wzv.z, b1.y * wzv.w)));
            #pragma unroll
            for (int m = 1; m < 64; m <<= 1) zp += __shfl_xor(zp, m, 64);
            if (lane == 0) zred[par][half][wid & 3] = zp;
        }

        // ---- owner: combine 8 wave partials, update state, write out ----
        if (own) {
            float rec = 0.f;
            const float* redf = (const float*)red4;
            #pragma unroll
            for (int wv = 0; wv < 8; ++wv)
                rec += redf[(wv * 72 + il_o * 9 + (ob >> 2)) * 4 + (ob & 3)];

            float xv = fmaf(xa.x, wih[0], fmaf(xa.y, wih[1],
                       fmaf(xa.z, wih[2], xa.w * wih[3])));
            xv = fmaf(xb.x, wih[4], fmaf(xb.y, wih[5],
                 fmaf(xb.z, wih[6], fmaf(xb.w, wih[7], xv))));

            float drive = 0.5f * (1.0f + htr);
            float rn = r + ((p - r) / 0.2f - 10.0f * r * drive) * 0.001f;
            float un = u + ((p - u) / 1.5f + 10.0f * (1.0f - u) * drive) * 0.001f;
            float hn = h + ((-h + xv + rec) / 0.01f) * 0.001f;
            float htn = tanhf(hn);

            out[OFF_H + (ob * TSTEPS + t) * NH + oi] = hn;
            out[OFF_R + (ob * TSTEPS + t) * NH + oi] = rn;
            out[OFF_U + (ob * TSTEPS + t) * NH + oi] = un;

            __hip_atomic_store(&AT[((t + 1) & 1) * NH * NB + oi * NB + ob],
                               rn * sc * htn,
                               __ATOMIC_RELAXED, __HIP_MEMORY_SCOPE_AGENT);
            __hip_atomic_store(&HT[(t & 1) * NB * NH + ob * NH + oi], htn,
                               __ATOMIC_RELAXED, __HIP_MEMORY_SCOPE_AGENT);

            h = hn; r = rn; u = un; htr = htn;
        }

        gridbar(slot, g, stamp); ++stamp;
    }

    // ---- epilogue: finalize z[998] (zred[0], written at t=999) ----
    if (zt == 0) {
        float z = zred[0][half][0] + zred[0][half][1]
                + zred[0][half][2] + zred[0][half][3];
        out[OFF_Z + (bz * TSTEPS + 998) * NO + oz] = z;
    }
    // ---- partial + finalize z[999] from HT[1] ----
    {
        const float* HTp = HT + 1 * NB * NH + bz * NH + 4 * zt;
        float2 b0 = __builtin_bit_cast(float2,
            __hip_atomic_load((const u64*)HTp,
                              __ATOMIC_RELAXED, __HIP_MEMORY_SCOPE_AGENT));
        float2 b1 = __builtin_bit_cast(float2,
            __hip_atomic_load((const u64*)(HTp + 2),
                              __ATOMIC_RELAXED, __HIP_MEMORY_SCOPE_AGENT));
        float zp = fmaf(b0.x, wzv.x, fmaf(b0.y, wzv.y,
                   fmaf(b1.x, wzv.z, b1.y * wzv.w)));
        #pragma unroll
        for (int m = 1; m < 64; m <<= 1) zp += __shfl_xor(zp, m, 64);
        if (lane == 0) zred[1][half][wid & 3] = zp;
    }
    __syncthreads();
    if (zt == 0) {
        float z = zred[1][half][0] + zred[1][half][1]
                + zred[1][half][2] + zred[1][half][3];
        out[OFF_Z + (bz * TSTEPS + 999) * NO + oz] = z;
    }
}

extern "C" void kernel_launch(void* const* d_in, const int* in_sizes, int n_in,
                              void* d_out, int out_size, void* d_ws, size_t ws_size,
                              hipStream_t stream) {
    const float* x     = (const float*)d_in[0];
    const float* h0    = (const float*)d_in[1];
    const float* r0    = (const float*)d_in[2];
    const float* u0    = (const float*)d_in[3];
    const float* prel  = (const float*)d_in[4];
    const float* scal  = (const float*)d_in[5];
    const float* Wih   = (const float*)d_in[6];
    const float* Whh   = (const float*)d_in[7];
    const float* Wmask = (const float*)d_in[8];
    const float* Whz   = (const float*)d_in[9];
    float* out = (float*)d_out;
    float* ws  = (float*)d_ws;

    // Zero the 128 barrier slots (128B apart) each launch.
    hipMemsetAsync(d_ws, 0, NWG * 128, stream);

    void* args[] = { &x, &h0, &r0, &u0, &prel, &scal,
                     &Wih, &Whh, &Wmask, &Whz, &out, &ws };
    hipLaunchCooperativeKernel((void*)rnn_stp_kernel, dim3(NWG), dim3(BLK),
                               args, 0, stream);
}

// Round 7
// 9288.901 us; speedup vs baseline: 2.0787x; 2.0787x over previous
//
#include <hip/hip_runtime.h>
#include <math.h>

// RNN with short-term plasticity: persistent cooperative kernel, 1 grid
// barrier per time step.
//
// Round 7: round-4 compute structure (w[4][16]=64 regs/thread, NWG=256,
// fits the de-facto 128-VGPR cap -- rounds 5/6 proved the allocator
// ignores launch_bounds and spills ~100 regs = 21 GB/launch scratch).
// New: traffic-minimal barrier. Round-4 polled 256 threads/WG on 256
// slots spread over 128B strides = tens of MB/step of coherence-point
// traffic contending with the A broadcast. Now slots are packed (4B
// stride, 16 lines); only wave 0 polls: lane l loads its 4 slots as
// 2xu64, __all() exits. Plus round-5's double-buffered zred (no 2nd
// syncthreads per step).
//
#define NH 1024
#define NB 32
#define NI 8
#define NO 8
#define TSTEPS 1000

#define NWG 256
#define BLK 512

// d_out float offsets (z, h, r, u concatenated flat)
#define OFF_Z 0
#define OFF_H (NB * TSTEPS * NO)            // 256000
#define OFF_R (OFF_H + NB * TSTEPS * NH)    // 33024000
#define OFF_U (OFF_R + NB * TSTEPS * NH)    // 65792000

// d_ws float offsets: slots[256] packed (1 KB), AT[2][NH][NB], HT[2][NB][NH]
#define WS_AT 2048                          // float index (8 KB byte offset)
#define WS_HT (WS_AT + 2 * NH * NB)

typedef unsigned long long u64;

// Barrier: WG g stamps slot[g] (packed 4B stride) with the step number via
// a coherent store; wave 0 polls all 256 slots (4 per lane, 2xu64 loads).
// Release ordering: the leading __syncthreads drains vmcnt in every wave
// (all agent-scope data stores ack'd at the coherence point) before thread
// 0 stores the stamp. Readers' data loads are agent-scope (bypass L1/L2),
// so no acquire fence is needed.
__device__ __forceinline__ void gridbar(unsigned* slot, int g, unsigned stamp) {
    __syncthreads();
    if (threadIdx.x == 0)
        __hip_atomic_store(&slot[g], stamp,
                           __ATOMIC_RELAXED, __HIP_MEMORY_SCOPE_AGENT);
    if (threadIdx.x < 64) {
        const u64* p = (const u64*)(slot + threadIdx.x * 4);
        for (;;) {
            u64 v0 = __hip_atomic_load(p,     __ATOMIC_RELAXED, __HIP_MEMORY_SCOPE_AGENT);
            u64 v1 = __hip_atomic_load(p + 1, __ATOMIC_RELAXED, __HIP_MEMORY_SCOPE_AGENT);
            unsigned a = (unsigned)v0, b = (unsigned)(v0 >> 32);
            unsigned c = (unsigned)v1, d = (unsigned)(v1 >> 32);
            bool ok = (a >= stamp) & (b >= stamp) & (c >= stamp) & (d >= stamp);
            if (__all(ok)) break;
            __builtin_amdgcn_s_sleep(1);
        }
    }
    __syncthreads();
}

__global__ __launch_bounds__(BLK, 2) void rnn_stp_kernel(
    const float* __restrict__ x,     // [32][1000][8]
    const float* __restrict__ h0,    // [32][1024]
    const float* __restrict__ r0,    // [32][1024]
    const float* __restrict__ u0,    // [32][1024]
    const float* __restrict__ prel,  // [1024]
    const float* __restrict__ scal,  // [1024]
    const float* __restrict__ Wih,   // [1024][8]
    const float* __restrict__ Whh,   // [1024][1024]
    const float* __restrict__ Wmask, // [1024][1024]
    const float* __restrict__ Whz,   // [8][1024]
    float* __restrict__ out,
    float* __restrict__ ws)
{
    const int tid = threadIdx.x;
    const int g   = blockIdx.x;

    unsigned* slot = (unsigned*)ws;
    float* AT = ws + WS_AT;   // [2][NH][NB]
    float* HT = ws + WS_HT;   // [2][NB][NH]

    // XCD swizzle: XCD x (= g&7) owns neurons [128x, 128x+128) so 64B output
    // lines (16 neurons) are fully assembled within one XCD's L2.
    const int chunk = (g & 7) * 32 + (g >> 3);
    const int ib = chunk * 4;                 // first of 4 owned neurons

    __shared__ float4 red4[8 * 36];           // [wid][il*9+bg]
    __shared__ float zred[2][8];              // [parity][wid]

    // ---- GEMM roles: ks = tid>>3 (j in [ks*16,+16)), bg = tid&7 (4 b) ----
    const int ks = tid >> 3;
    const int bg = tid & 7;

    // Weights for 4 owned rows x this thread's 16-j slice (64 VGPRs).
    float w[4][16];
    #pragma unroll
    for (int il = 0; il < 4; ++il) {
        const float* wp = Whh   + (ib + il) * NH + ks * 16;
        const float* mp = Wmask + (ib + il) * NH + ks * 16;
        #pragma unroll
        for (int jj = 0; jj < 16; ++jj) w[il][jj] = wp[jj] * mp[jj];
    }

    // ---- z role: WG g computes z[b=g>>3][o=g&7] ----
    const int bz = g >> 3, oz = g & 7;
    const float wz0 = Whz[oz * NH + 2 * tid];
    const float wz1 = Whz[oz * NH + 2 * tid + 1];

    // ---- owner role: tid<128, b = tid>>2, neuron = ib + (tid&3) ----
    const bool own = tid < 128;
    const int ob   = tid >> 2;
    const int il_o = tid & 3;
    const int oi   = ib + il_o;
    float h = 0.f, r = 0.f, u = 0.f, htr = 0.f, p = 0.f, sc = 0.f;
    float wih[8];
    if (own) {
        h  = h0[ob * NH + oi];
        r  = r0[ob * NH + oi];
        u  = u0[ob * NH + oi];
        p  = prel[oi];
        sc = scal[oi];
        #pragma unroll
        for (int k = 0; k < 8; ++k) wih[k] = Wih[oi * NI + k];
        htr = tanhf(h);
        __hip_atomic_store(&AT[oi * NB + ob], r * sc * htr,
                           __ATOMIC_RELAXED, __HIP_MEMORY_SCOPE_AGENT);
    }

    unsigned stamp = 1;
    gridbar(slot, g, stamp); ++stamp;

    const int lane = tid & 63, wid = tid >> 6;

    for (int t = 0; t < TSTEPS; ++t) {
        const int cur = t & 1;

        // ---- coherent A loads: unique 16 j x 4 b slice (32 x 8B loads) ----
        const float* Ab = AT + cur * NH * NB + ks * 16 * NB + bg * 4;
        float2 a[16][2];
        #pragma unroll
        for (int jj = 0; jj < 16; ++jj) {
            u64 lo = __hip_atomic_load((const u64*)(Ab + jj * NB),
                                       __ATOMIC_RELAXED, __HIP_MEMORY_SCOPE_AGENT);
            u64 hi = __hip_atomic_load((const u64*)(Ab + jj * NB + 2),
                                       __ATOMIC_RELAXED, __HIP_MEMORY_SCOPE_AGENT);
            a[jj][0] = __builtin_bit_cast(float2, lo);
            a[jj][1] = __builtin_bit_cast(float2, hi);
        }

        // ---- x prefetch (cached; read-only data) ----
        float4 xa = make_float4(0.f, 0.f, 0.f, 0.f), xb = xa;
        if (own) {
            const float4* xp = (const float4*)(x + (ob * TSTEPS + t) * NI);
            xa = xp[0];
            xb = xp[1];
        }

        // ---- FMAs: 16 j x 4 il x 4 b ----
        float acc[4][4] = {{0.f,0.f,0.f,0.f},{0.f,0.f,0.f,0.f},
                           {0.f,0.f,0.f,0.f},{0.f,0.f,0.f,0.f}};
        #pragma unroll
        for (int jj = 0; jj < 16; ++jj) {
            #pragma unroll
            for (int il = 0; il < 4; ++il) {
                const float wv = w[il][jj];
                acc[il][0] = fmaf(a[jj][0].x, wv, acc[il][0]);
                acc[il][1] = fmaf(a[jj][0].y, wv, acc[il][1]);
                acc[il][2] = fmaf(a[jj][1].x, wv, acc[il][2]);
                acc[il][3] = fmaf(a[jj][1].y, wv, acc[il][3]);
            }
        }

        // ---- in-wave butterfly over ks bits (lane bits 3..5) ----
        #pragma unroll
        for (int m = 8; m <= 32; m <<= 1) {
            #pragma unroll
            for (int il = 0; il < 4; ++il) {
                #pragma unroll
                for (int q = 0; q < 4; ++q)
                    acc[il][q] += __shfl_xor(acc[il][q], m, 64);
            }
        }
        if (lane < 8) {   // lane == bg; holds wave-sum over its 8 ks groups
            #pragma unroll
            for (int il = 0; il < 4; ++il)
                red4[wid * 36 + il * 9 + lane] =
                    make_float4(acc[il][0], acc[il][1], acc[il][2], acc[il][3]);
        }
        __syncthreads();

        // ---- finalize z[t-2] (zred written at step t-1, gridbar-ordered) ----
        if (t >= 2 && tid == 0) {
            const int fpar = t & 1;   // == (t-2)&1
            float z = 0.f;
            #pragma unroll
            for (int wv = 0; wv < 8; ++wv) z += zred[fpar][wv];
            out[OFF_Z + (bz * TSTEPS + (t - 2)) * NO + oz] = z;
        }
        // ---- partial z[t-1] from HT[(t-1)&1] (coherent read) ----
        if (t >= 1) {
            const int par = (t - 1) & 1;
            u64 hv = __hip_atomic_load(
                (const u64*)(HT + par * NB * NH + bz * NH + 2 * tid),
                __ATOMIC_RELAXED, __HIP_MEMORY_SCOPE_AGENT);
            float2 ht2 = __builtin_bit_cast(float2, hv);
            float zp = fmaf(ht2.x, wz0, ht2.y * wz1);
            #pragma unroll
            for (int m = 1; m < 64; m <<= 1) zp += __shfl_xor(zp, m, 64);
            if (lane == 0) zred[par][wid] = zp;
        }

        // ---- owner: combine 8 wave partials, update state, write out ----
        if (own) {
            float rec = 0.f;
            const float* redf = (const float*)red4;
            #pragma unroll
            for (int wv = 0; wv < 8; ++wv)
                rec += redf[(wv * 36 + il_o * 9 + (ob >> 2)) * 4 + (ob & 3)];

            float xv = fmaf(xa.x, wih[0], fmaf(xa.y, wih[1],
                       fmaf(xa.z, wih[2], xa.w * wih[3])));
            xv = fmaf(xb.x, wih[4], fmaf(xb.y, wih[5],
                 fmaf(xb.z, wih[6], fmaf(xb.w, wih[7], xv))));

            float drive = 0.5f * (1.0f + htr);
            float rn = r + ((p - r) / 0.2f - 10.0f * r * drive) * 0.001f;
            float un = u + ((p - u) / 1.5f + 10.0f * (1.0f - u) * drive) * 0.001f;
            float hn = h + ((-h + xv + rec) / 0.01f) * 0.001f;
            float htn = tanhf(hn);

            out[OFF_H + (ob * TSTEPS + t) * NH + oi] = hn;
            out[OFF_R + (ob * TSTEPS + t) * NH + oi] = rn;
            out[OFF_U + (ob * TSTEPS + t) * NH + oi] = un;

            __hip_atomic_store(&AT[((t + 1) & 1) * NH * NB + oi * NB + ob],
                               rn * sc * htn,
                               __ATOMIC_RELAXED, __HIP_MEMORY_SCOPE_AGENT);
            __hip_atomic_store(&HT[(t & 1) * NB * NH + ob * NH + oi], htn,
                               __ATOMIC_RELAXED, __HIP_MEMORY_SCOPE_AGENT);

            h = hn; r = rn; u = un; htr = htn;
        }

        gridbar(slot, g, stamp); ++stamp;
    }

    // ---- epilogue: finalize z[998] (zred[0], written at t=999) ----
    if (tid == 0) {
        float z = 0.f;
        #pragma unroll
        for (int wv = 0; wv < 8; ++wv) z += zred[0][wv];
        out[OFF_Z + (bz * TSTEPS + 998) * NO + oz] = z;
    }
    // ---- partial + finalize z[999] from HT[1] ----
    {
        u64 hv = __hip_atomic_load(
            (const u64*)(HT + 1 * NB * NH + bz * NH + 2 * tid),
            __ATOMIC_RELAXED, __HIP_MEMORY_SCOPE_AGENT);
        float2 ht2 = __builtin_bit_cast(float2, hv);
        float zp = fmaf(ht2.x, wz0, ht2.y * wz1);
        #pragma unroll
        for (int m = 1; m < 64; m <<= 1) zp += __shfl_xor(zp, m, 64);
        if (lane == 0) zred[1][wid] = zp;
    }
    __syncthreads();
    if (tid == 0) {
        float z = 0.f;
        #pragma unroll
        for (int wv = 0; wv < 8; ++wv) z += zred[1][wv];
        out[OFF_Z + (bz * TSTEPS + 999) * NO + oz] = z;
    }
}

extern "C" void kernel_launch(void* const* d_in, const int* in_sizes, int n_in,
                              void* d_out, int out_size, void* d_ws, size_t ws_size,
                              hipStream_t stream) {
    const float* x     = (const float*)d_in[0];
    const float* h0    = (const float*)d_in[1];
    const float* r0    = (const float*)d_in[2];
    const float* u0    = (const float*)d_in[3];
    const float* prel  = (const float*)d_in[4];
    const float* scal  = (const float*)d_in[5];
    const float* Wih   = (const float*)d_in[6];
    const float* Whh   = (const float*)d_in[7];
    const float* Wmask = (const float*)d_in[8];
    const float* Whz   = (const float*)d_in[9];
    float* out = (float*)d_out;
    float* ws  = (float*)d_ws;

    // Zero the 256 packed barrier slots each launch.
    hipMemsetAsync(d_ws, 0, NWG * sizeof(unsigned), stream);

    void* args[] = { &x, &h0, &r0, &u0, &prel, &scal,
                     &Wih, &Whh, &Wmask, &Whz, &out, &ws };
    hipLaunchCooperativeKernel((void*)rnn_stp_kernel, dim3(NWG), dim3(BLK),
                               args, 0, stream);
}